// Round 8
// baseline (1049.915 us; speedup 1.0000x reference)
//
#include <hip/hip_runtime.h>

// MOGCN on MI355X. Pipeline:
//  k_prep     : merged prep (R13): bitpack v2 / xconv v2 / build_wb / wb a-dots
//  k_boolmm   : boolean power masks; run2 computes adj^3 = adj * adj^2 (sparse A)
//  k_gemm_h   : X@W bf16 MFMA -> h + f1L/f2L + etab (R12 dbuf stage-ahead)
//  k_rowstats : log2-domain softmax stats -> per-row E1, E2, PZ
//  k_attgemm  : R16. Dense path (kl=1,2) = R9 verbatim. kl=0 blocks (g<16) take a
//               SPARSE path: level-0 masks are ~1% dense (~10 nbrs/row), so the
//               dense MFMA slice multiplied 99% zeros. Sparse: per row walk active
//               mask BYTES (8-j groups); per group: p = maskbit & max(e1k*E1,
//               e2k*E2) (same R9 formula), gather h from the swizzled layout -
//               each 16B chunk holds 8 consecutive j at one f, so the wave's
//               4x dwordx4/lane exactly tile the group's 4KB (line-efficient).
//               Unpack-FMA f32 accumulate; empty rows (PZ!=0, ~2 global) full-scan.
//               No LDS/barriers; block-uniform branch. Sparse wall ~50us hides
//               under the 2-dense-blocks/CU wall (~2/3 * 131).
//  k_scorecomb: R15 fusion of k_score + k_combine.
//
// Workspace map (bytes), total 159,842,304 (~152.4 MiB):
//  [0)            Xs bf16 16,777,216 | Wb bf16 @16,777,216 (2,490,368)  -- dead after k_gemm_h
//  [0)            H32 fp32 50,331,648 (reuses region above; fully written by k_attgemm)
//  [50,331,648)   hsw bf16 75,497,472   [9][16][128][256][8]
//  [125,829,120)  mbA u64 12,582,912; lvl0 dead after boolmm-1 -> rowE1/rowE2/rowPZ
//  [138,412,032)  mbT u64 18,874,368    [9][16][16w][1024i]
//  [157,286,400)  fbuf fp32 1,179,648   [2][9][16384]  (values pre-scaled by log2e)
//  [158,466,048)  etab1 589,824 | [159,055,872) etab2 589,824

typedef unsigned long long u64;
typedef __attribute__((ext_vector_type(4))) float f32x4;
typedef __attribute__((ext_vector_type(8))) short bf16x8;

#define NEGF (-9.0e15f)
#define L2E 1.44269504f

__device__ __forceinline__ float fexp2(float x){
#if __has_builtin(__builtin_amdgcn_exp2f)
  return __builtin_amdgcn_exp2f(x);
#else
  return exp2f(x);
#endif
}
__device__ __forceinline__ float flog2(float x){
#if __has_builtin(__builtin_amdgcn_logf)
  return __builtin_amdgcn_logf(x);
#else
  return log2f(x);
#endif
}
__device__ __forceinline__ float frcp(float x){
#if __has_builtin(__builtin_amdgcn_rcpf)
  return __builtin_amdgcn_rcpf(x);
#else
  return 1.0f/x;
#endif
}
__device__ __forceinline__ unsigned short f2bf(float x){   // RNE
  union { float f; unsigned u; } a; a.f = x;
  unsigned r = a.u + 0x7FFFu + ((a.u >> 16) & 1u);
  return (unsigned short)(r >> 16);
}
__device__ __forceinline__ float bf2f(unsigned short h){
  union { unsigned u; float f; } a; a.u = ((unsigned)h) << 16; return a.f;
}
__device__ __forceinline__ float bfl(unsigned u){ return __uint_as_float(u << 16); }
__device__ __forceinline__ float bfh(unsigned u){ return __uint_as_float(u & 0xFFFF0000u); }
__device__ __forceinline__ unsigned pack_bf16x2(float lo, float hi){ // fast round
  union { float f; unsigned u; } a, b; a.f = lo; b.f = hi;
  unsigned ul = a.u + 0x8000u, uh = b.u + 0x8000u;
#if __has_builtin(__builtin_amdgcn_perm)
  return __builtin_amdgcn_perm(uh, ul, 0x07060302u);
#else
  return (ul >> 16) | (uh & 0xFFFF0000u);
#endif
}
__device__ __forceinline__ float tanh_fast(float x){
  float e = fexp2(x * 2.885390082f);  // exp(2x)
  return 1.0f - 2.0f*frcp(e + 1.0f);
}
__device__ __forceinline__ void async_cp16(void* lds, const void* g){
  __builtin_amdgcn_global_load_lds(
      (const __attribute__((address_space(1))) unsigned int*)g,
      (__attribute__((address_space(3))) unsigned int*)lds, 16, 0, 0);
}

// ---------------- merged prep kernel (R13) ----------------

__global__ void k_prep(const float* __restrict__ adj, const float* __restrict__ X,
                       const float* __restrict__ W, const float* __restrict__ a1,
                       const float* __restrict__ a2,
                       u64* __restrict__ mbA0, u64* __restrict__ mbT,
                       unsigned short* __restrict__ Xs, unsigned short* __restrict__ Wb)
{
  int blk = blockIdx.x;
  const int lane = threadIdx.x & 63;
  if (blk < 3072) {
    // ---- bitpack v2: wave <-> contiguous 4KB chunk (64 words) ----
    int wg = blk*4 + (threadIdx.x >> 6);        // chunk id 0..12287
    const float* ap = adj + (size_t)wg*4096;
    u64 mine = 0;
#pragma unroll
    for (int j = 0; j < 64; ++j) {
      u64 m = __ballot(ap[j*64 + lane] > 0.0f);
      if (lane == j) mine = m;
    }
    int Wd = wg*64 + lane;                      // word = ((b*3+t)*1024 + i)*16 + w
    int w = Wd & 15, i = (Wd >> 4) & 1023, bt = Wd >> 14;
    int t = bt % 3, b = bt / 3;                 // bt uniform per wave (4KB < bt block)
    mbA0[((size_t)(t*16 + b)*1024 + i)*16 + w] = mine;   // coalesced 512B per wave
    mbT[((size_t)(t*16 + b)*16 + w)*1024 + i] = mine;    // 16 x 32B segments
  } else if (blk < 5120) {
    // ---- xconv v2: lane reads one full 64B line (16 floats = 2 g-groups) ----
    int wg = (blk - 3072)*4 + (threadIdx.x >> 6);   // 0..8191
    int g2 = wg & 31;
    int bn = (wg >> 5)*64 + lane;
    const float* xp = X + (size_t)bn*512 + g2*16;
    float4 A = *(const float4*)(xp);
    float4 B = *(const float4*)(xp + 4);
    float4 C = *(const float4*)(xp + 8);
    float4 D = *(const float4*)(xp + 12);
    ushort4 lo, hi;
    lo.x=f2bf(A.x); lo.y=f2bf(A.y); lo.z=f2bf(A.z); lo.w=f2bf(A.w);
    hi.x=f2bf(B.x); hi.y=f2bf(B.y); hi.z=f2bf(B.z); hi.w=f2bf(B.w);
    ushort4* d0 = (ushort4*)(Xs + ((size_t)(2*g2)*16384 + bn)*8);
    d0[0] = lo; d0[1] = hi;
    lo.x=f2bf(C.x); lo.y=f2bf(C.y); lo.z=f2bf(C.z); lo.w=f2bf(C.w);
    hi.x=f2bf(D.x); hi.y=f2bf(D.y); hi.z=f2bf(D.z); hi.w=f2bf(D.w);
    ushort4* d1 = (ushort4*)(Xs + ((size_t)(2*g2 + 1)*16384 + bn)*8);
    d1[0] = lo; d1[1] = hi;
  } else if (blk < 5728) {
    // ---- build_wb main (transpose copy + zero fill; a-dots done by blk>=5728) ----
    int idx = (blk - 5120)*256 + threadIdx.x;       // g*2432 + c
    if (idx >= 64*2432) return;
    int c = idx % 2432, g = idx / 2432;
    unsigned short o[8];
    if (c < 2304) {
      int s = c >> 8, f = c & 255, t = s % 3, klq = s / 3;   // s = kl*3 + t
      const float* wp = W + ((size_t)(t*3 + klq)*512)*256 + f;
#pragma unroll
      for (int e = 0; e < 8; ++e) o[e] = f2bf(wp[(size_t)(g*8 + e)*256]);
    } else if (c >= 2322) {
#pragma unroll
      for (int e = 0; e < 8; ++e) o[e] = 0;
    } else {
      return;                                      // a-dot columns: dedicated waves
    }
    ushort4 lo, hi;
    lo.x=o[0]; lo.y=o[1]; lo.z=o[2]; lo.w=o[3];
    hi.x=o[4]; hi.y=o[5]; hi.z=o[6]; hi.w=o[7];
    ushort4* dst = (ushort4*)(Wb + (size_t)idx*8);
    dst[0] = lo; dst[1] = hi;
  } else {
    // ---- wb a-dots: one wave per (g, c2), lane-parallel over f ----
    int dw = (blk - 5728)*4 + (threadIdx.x >> 6);   // 0..1151
    if (dw >= 1152) return;
    int c2 = dw % 18, g = dw / 18;
    int s = c2 >> 1, t = s % 3, klq = s / 3;
    const float* av = ((c2 & 1) ? a2 : a1) + (t*3 + klq)*256;
    const float* wp = W + (size_t)(t*3 + klq)*512*256;
    float4 a4 = *(const float4*)(av + lane*4);
    unsigned short o[8];
#pragma unroll
    for (int e = 0; e < 8; ++e) {
      const float* wr = wp + (size_t)(g*8 + e)*256 + lane*4;
      float4 w4 = *(const float4*)(wr);
      float acc = w4.x*a4.x + w4.y*a4.y + w4.z*a4.z + w4.w*a4.w;
#pragma unroll
      for (int off = 32; off; off >>= 1) acc += __shfl_xor(acc, off);
      o[e] = f2bf(acc);
    }
    if (lane == 0) {
      int c = 2304 + c2;
      ushort4 lo, hi;
      lo.x=o[0]; lo.y=o[1]; lo.z=o[2]; lo.w=o[3];
      hi.x=o[4]; hi.y=o[5]; hi.z=o[6]; hi.w=o[7];
      ushort4* dst = (ushort4*)(Wb + ((size_t)g*2432 + c)*8);
      dst[0] = lo; dst[1] = hi;
    }
  }
}

__global__ void k_boolmm(const u64* __restrict__ A, const u64* __restrict__ Bm,
                         u64* __restrict__ outA, u64* __restrict__ outT, int sbase)
{
  int tid = blockIdx.x*256 + threadIdx.x;   // 48*1024*16
  int w = tid & 15, i = (tid >> 4) & 1023, tb = tid >> 14;
  const u64* Ar = A + ((size_t)tb*1024 + i)*16;
  const u64* Bb = Bm + (size_t)tb*16384;
  u64 acc = 0;
  for (int ww = 0; ww < 16; ++ww) {
    u64 aw = Ar[ww];
    while (aw) {
      int kk = __builtin_ctzll(aw);
      aw &= aw - 1;
      acc |= Bb[((size_t)(ww*64 + kk))*16 + w];
    }
  }
  if (outA) outA[((size_t)tb*1024 + i)*16 + w] = acc;
  int t = tb >> 4, bq = tb & 15;
  outT[(((size_t)(sbase + t)*16 + bq)*16 + w)*1024 + i] = acc;
}

// ---------------- h = X@W GEMM (bf16 MFMA), fused f1L/f2L + etab ----------------
// R12: 16 half-steps of 32 k; half-tiles double-buffered; stage-ahead skeleton.

__global__ __launch_bounds__(256) void k_gemm_h(
    const unsigned short* __restrict__ Xs, const unsigned short* __restrict__ Wb,
    unsigned short* __restrict__ hsw, float* __restrict__ fbuf,
    float* __restrict__ et1, float* __restrict__ et2)
{
  __shared__ unsigned short Asl[2*4*132*8 + 8];   // 2 half-buffers x [4 kg][132][8]
  __shared__ unsigned short Bsl[2*4*132*8 + 8];
  const int tid = threadIdx.x, lane = tid & 63, wid = tid >> 6;
  int vb = blockIdx.x;                       // XCD swizzle: same mt -> same XCD
  int xc = vb & 7, mrest = vb >> 3;
  int mt = xc + 8*(mrest/19), nt = mrest % 19;
  const int M0 = mt << 7, N0 = nt << 7;
  const int wr = (wid >> 1) << 6, wc = (wid & 1) << 6;
  const int me = lane & 15;
  const int kgl = lane >> 4;                 // k-group within half (0..3)
  f32x4 acc[4][4] = {};

  // stage half 0: wave wid stages k-group wid (A rows 0..127, B cols 0..127)
  {
    const unsigned short* gA = Xs + ((size_t)wid*16384 + (M0 + lane))*8;
    const unsigned short* gB = Wb + ((size_t)wid*2432  + (N0 + lane))*8;
    unsigned short* la = Asl + (wid*132)*8;
    unsigned short* lb = Bsl + (wid*132)*8;
    async_cp16(la,        gA);
    async_cp16(la + 64*8, gA + (size_t)64*8);
    async_cp16(lb,        gB);
    async_cp16(lb + 64*8, gB + (size_t)64*8);
  }

  for (int h = 0; h < 16; ++h) {
    __syncthreads();                         // drains vmcnt: half-h loads landed
    if (h + 1 < 16) {                        // stage half h+1 into other buffer
      int kg = (h + 1)*4 + wid;
      const unsigned short* gA = Xs + ((size_t)kg*16384 + (M0 + lane))*8;
      const unsigned short* gB = Wb + ((size_t)kg*2432  + (N0 + lane))*8;
      unsigned short* la = Asl + (((h + 1 & 1)*4 + wid)*132)*8;
      unsigned short* lb = Bsl + (((h + 1 & 1)*4 + wid)*132)*8;
      async_cp16(la,        gA);
      async_cp16(la + 64*8, gA + (size_t)64*8);
      async_cp16(lb,        gB);
      async_cp16(lb + 64*8, gB + (size_t)64*8);
    }
    const unsigned short* Ah = Asl + ((h & 1)*4*132)*8;
    const unsigned short* Bh = Bsl + ((h & 1)*4*132)*8;
    bf16x8 afr[4], bfr[4];
#pragma unroll
    for (int rb = 0; rb < 4; ++rb)
      afr[rb] = *(const bf16x8*)(Ah + (kgl*132 + wr + rb*16 + me)*8);
#pragma unroll
    for (int cb = 0; cb < 4; ++cb)
      bfr[cb] = *(const bf16x8*)(Bh + (kgl*132 + wc + cb*16 + me)*8);
#pragma unroll
    for (int rb = 0; rb < 4; ++rb)
#pragma unroll
      for (int cb = 0; cb < 4; ++cb)
        acc[rb][cb] = __builtin_amdgcn_mfma_f32_16x16x32_bf16(afr[rb], bfr[cb], acc[rb][cb], 0, 0, 0);
  }

  const int quad = lane >> 4;
#pragma unroll
  for (int rb = 0; rb < 4; ++rb) {
    int jbase = M0 + wr + rb*16 + quad*4;
    int bidx = jbase >> 10, jn = jbase & 1023;
#pragma unroll
    for (int cb = 0; cb < 4; ++cb) {
      int c = N0 + wc + cb*16 + me;
      f32x4 v = acc[rb][cb];
      if (c < 2304) {
        int s = c >> 8, f = c & 255;
        ushort4 pk;
        pk.x = f2bf(v[0]); pk.y = f2bf(v[1]); pk.z = f2bf(v[2]); pk.w = f2bf(v[3]);
        *(ushort4*)(hsw + (size_t)s*4194304 + (size_t)bidx*262144 + ((jn>>3)*256 + f)*8 + (jn&7)) = pk;
      } else if (c < 2322) {
        int c2 = c - 2304, s = c2 >> 1, wh = c2 & 1;
        f32x4 vl = v * L2E;                   // log2 domain
        *(f32x4*)(fbuf + (size_t)wh*147456 + s*16384 + jbase) = vl;
        if (wh) {                             // etab fold: e1k=2^f2L, e2k=2^(.2 f2L)
#pragma unroll
          for (int r = 0; r < 4; ++r) {
            et1[s*16384 + jbase + r] = fexp2(vl[r]);
            et2[s*16384 + jbase + r] = fexp2(0.2f*vl[r]);
          }
        }
      }
    }
  }
}

// ---------------- per-row softmax stats (log2 domain internally) ----------------

__global__ __launch_bounds__(256) void k_rowstats(
    const u64* __restrict__ mbT, const float* __restrict__ fbuf,
    float* __restrict__ rowE1, float* __restrict__ rowE2, float* __restrict__ rowPZ)
{
  int gw = blockIdx.x*4 + (threadIdx.x >> 6);   // row id: (s*16+b)*1024 + i
  int lane = threadIdx.x & 63;
  int i = gw & 1023, sb = gw >> 10;
  int b = sb & 15, s = sb >> 4;
  const u64* mrow = mbT + (size_t)sb*16384 + i;
  const float* f1g = fbuf + s*16384 + b*1024;
  const float* f2g = fbuf + 147456 + s*16384 + b*1024;
  float f1i = f1g[i];
  float vals[16];
  float mmax = NEGF;
#pragma unroll
  for (int w = 0; w < 16; ++w) {
    u64 word = mrow[(size_t)w*1024];
    float u0 = f1i + f2g[w*64 + lane];          // (f1+f2)*log2e
    float lk = fmaxf(u0, 0.2f*u0);              // leaky in log2 domain
    float val = ((word >> lane) & 1ull) ? lk : NEGF;
    vals[w] = val;
    mmax = fmaxf(mmax, val);
  }
#pragma unroll
  for (int off = 32; off; off >>= 1) mmax = fmaxf(mmax, __shfl_xor(mmax, off));
  float l = 0.0f;
#pragma unroll
  for (int w = 0; w < 16; ++w) l += fexp2(vals[w] - mmax);
#pragma unroll
  for (int off = 32; off; off >>= 1) l += __shfl_xor(l, off);
  if (lane == 0) {
    bool empty = (mmax < -8.0e15f);
    float C = (empty ? 0.0f : -mmax) - flog2(l);
    rowE1[gw] = fexp2(f1i + C);
    rowE2[gw] = fexp2(0.2f*f1i + C);
    rowPZ[gw] = empty ? fexp2(C) : 0.0f;        // exact 0 for non-empty rows
  }
}

// ---------------- fused attention GEMM: H = sum_t softmax(mask_t(e_t)) @ h_t --------
// R16: kl=0 sparse path; kl=1,2 dense = R9 verbatim.

__global__ __launch_bounds__(256, 3) void k_attgemm(
    const unsigned short* __restrict__ hsw,
    const float* __restrict__ et1g, const float* __restrict__ et2g,
    const float* __restrict__ rowE1, const float* __restrict__ rowE2,
    const float* __restrict__ rowPZ,
    const u64* __restrict__ mbT, float* __restrict__ H32)
{
  __shared__ unsigned short Bts[2*4*260*8];   // 2 half-buffers, 16640B each (dense only)
  const int tid = threadIdx.x, lane = tid & 63, wid = tid >> 6;
  const int me = lane & 15, quad = lane >> 4;
  int vb = blockIdx.x;
  int mt = vb / 48, g = vb % 48;              // g%8 constant across a group's 16 blocks
  int kl = g >> 4, b = g & 15;
  const int i0w = mt*64 + wid*16;
  const int ir0 = i0w + me;

  if (g < 16) {
    // ---------- sparse path: kl=0, level-0 masks ~1% dense ----------
    const int f0 = lane*4;                    // this lane's 4 f-values
    for (int rloc = 0; rloc < 16; ++rloc) {
      const int i = i0w + rloc;
      float ac0 = 0.0f, ac1 = 0.0f, ac2 = 0.0f, ac3 = 0.0f;
#pragma unroll
      for (int tt = 0; tt < 3; ++tt) {
        const int rbi = tt*16384 + b*1024 + i;
        const float E1 = rowE1[rbi], E2 = rowE2[rbi], PZ = rowPZ[rbi];
        const u64* mrow = mbT + (size_t)b*16384 + (size_t)tt*262144 + i;
        const unsigned short* hb = hsw + (size_t)tt*4194304 + (size_t)b*262144;
        const float* e1t = et1g + tt*16384 + b*1024;
        const float* e2t = et2g + tt*16384 + b*1024;
        if (PZ == 0.0f) {                     // normal row: only masked j contribute
          for (int w = 0; w < 16; ++w) {
            u64 word = mrow[(size_t)w*1024];  // wave-uniform broadcast
            while (word) {                    // walk active BYTES (8-j groups)
              int bit = (int)__builtin_ctzll(word);
              int byi = bit >> 3;
              unsigned mby = (unsigned)((word >> (byi << 3)) & 0xFFull);
              word &= ~(0xFFull << (byi << 3));
              int jg = (w << 3) + byi;        // group of 8 j = [jg*8, jg*8+8)
              float4 eA = *(const float4*)(e1t + jg*8);
              float4 eB = *(const float4*)(e1t + jg*8 + 4);
              float4 eC = *(const float4*)(e2t + jg*8);
              float4 eD = *(const float4*)(e2t + jg*8 + 4);
              float pv0 = fmaxf(eA.x*E1, eC.x*E2);
              float pv1 = fmaxf(eA.y*E1, eC.y*E2);
              float pv2 = fmaxf(eA.z*E1, eC.z*E2);
              float pv3 = fmaxf(eA.w*E1, eC.w*E2);
              float pv4 = fmaxf(eB.x*E1, eD.x*E2);
              float pv5 = fmaxf(eB.y*E1, eD.y*E2);
              float pv6 = fmaxf(eB.z*E1, eD.z*E2);
              float pv7 = fmaxf(eB.w*E1, eD.w*E2);
              pv0 = __uint_as_float((unsigned)(-(int)((mby >> 0) & 1u)) & __float_as_uint(pv0));
              pv1 = __uint_as_float((unsigned)(-(int)((mby >> 1) & 1u)) & __float_as_uint(pv1));
              pv2 = __uint_as_float((unsigned)(-(int)((mby >> 2) & 1u)) & __float_as_uint(pv2));
              pv3 = __uint_as_float((unsigned)(-(int)((mby >> 3) & 1u)) & __float_as_uint(pv3));
              pv4 = __uint_as_float((unsigned)(-(int)((mby >> 4) & 1u)) & __float_as_uint(pv4));
              pv5 = __uint_as_float((unsigned)(-(int)((mby >> 5) & 1u)) & __float_as_uint(pv5));
              pv6 = __uint_as_float((unsigned)(-(int)((mby >> 6) & 1u)) & __float_as_uint(pv6));
              pv7 = __uint_as_float((unsigned)(-(int)((mby >> 7) & 1u)) & __float_as_uint(pv7));
              // swizzled h: 16B chunk = 8 consecutive j at one f; lane's 64B = its 4 f x 8 j
              const uint4* hq = (const uint4*)(hb + ((size_t)jg*256 + f0)*8);
              uint4 q0 = hq[0], q1 = hq[1], q2 = hq[2], q3 = hq[3];
              ac0 += pv0*bfl(q0.x) + pv1*bfh(q0.x) + pv2*bfl(q0.y) + pv3*bfh(q0.y)
                   + pv4*bfl(q0.z) + pv5*bfh(q0.z) + pv6*bfl(q0.w) + pv7*bfh(q0.w);
              ac1 += pv0*bfl(q1.x) + pv1*bfh(q1.x) + pv2*bfl(q1.y) + pv3*bfh(q1.y)
                   + pv4*bfl(q1.z) + pv5*bfh(q1.z) + pv6*bfl(q1.w) + pv7*bfh(q1.w);
              ac2 += pv0*bfl(q2.x) + pv1*bfh(q2.x) + pv2*bfl(q2.y) + pv3*bfh(q2.y)
                   + pv4*bfl(q2.z) + pv5*bfh(q2.z) + pv6*bfl(q2.w) + pv7*bfh(q2.w);
              ac3 += pv0*bfl(q3.x) + pv1*bfh(q3.x) + pv2*bfl(q3.y) + pv3*bfh(q3.y)
                   + pv4*bfl(q3.z) + pv5*bfh(q3.z) + pv6*bfl(q3.w) + pv7*bfh(q3.w);
            }
          }
        } else {                              // rare empty row: p = PZ for ALL j
          for (int jg = 0; jg < 128; ++jg) {
            const uint4* hq = (const uint4*)(hb + ((size_t)jg*256 + f0)*8);
            uint4 q0 = hq[0], q1 = hq[1], q2 = hq[2], q3 = hq[3];
            ac0 += PZ*(bfl(q0.x)+bfh(q0.x)+bfl(q0.y)+bfh(q0.y)+bfl(q0.z)+bfh(q0.z)+bfl(q0.w)+bfh(q0.w));
            ac1 += PZ*(bfl(q1.x)+bfh(q1.x)+bfl(q1.y)+bfh(q1.y)+bfl(q1.z)+bfh(q1.z)+bfl(q1.w)+bfh(q1.w));
            ac2 += PZ*(bfl(q2.x)+bfh(q2.x)+bfl(q2.y)+bfh(q2.y)+bfl(q2.z)+bfh(q2.z)+bfl(q2.w)+bfh(q2.w));
            ac3 += PZ*(bfl(q3.x)+bfh(q3.x)+bfl(q3.y)+bfh(q3.y)+bfl(q3.z)+bfh(q3.z)+bfl(q3.w)+bfh(q3.w));
          }
        }
      }
      f32x4 r; r[0] = ac0; r[1] = ac1; r[2] = ac2; r[3] = ac3;
      *(f32x4*)(H32 + (((size_t)b*1024 + i)*3 + 0)*256 + f0) = r;
    }
    return;
  }

  // ---------- dense path (kl = 1, 2): R9 verbatim ----------
  const unsigned short* hbase = hsw + (size_t)(kl*3)*4194304 + (size_t)b*262144;
  const float* e1b = et1g + (kl*3)*16384 + b*1024;   // e1k table
  const float* e2b = et2g + (kl*3)*16384 + b*1024;   // e2k table
  const float* E1b = rowE1 + ((kl*3)*16 + b)*1024;
  const float* E2b = rowE2 + ((kl*3)*16 + b)*1024;
  const float* PZb = rowPZ + ((kl*3)*16 + b)*1024;
  const u64* mb = mbT + (size_t)((kl*3)*16 + b)*16384;   // t-stride 262144 u64

  float E1v, E2v, PZv;
  int anyPZ = 0;
  f32x4 acc[16] = {};

  // seed: stage iter 0 (t=0, st=0, ks=0) into buffer 0
  {
    const unsigned short* hstage = hbase + wid*2048;
    unsigned short* lb = Bts + wid*2080;
#pragma unroll
    for (int c = 0; c < 4; ++c)
      async_cp16(lb + c*512, hstage + c*512 + lane*8);
  }
  u64 mw = mb[ir0];
  u64 nm = 0;

  for (int it = 0; it < 96; ++it) {
    const int tt = it >> 5, kk = it & 1;
    const int st = (it >> 1) & 15;
    if ((it & 31) == 0) {                 // t boundary: per-row constants for this t
      E1v = E1b[tt*16384 + ir0];
      E2v = E2b[tt*16384 + ir0];
      PZv = PZb[tt*16384 + ir0];
      anyPZ = __any(PZv != 0.0f);
    }
    if (!kk && it) mw = nm;               // adopt prefetched mask

    __syncthreads();   // drains vmcnt: current half's loads issued one compute ago

    if (it + 1 < 96) {                    // stage next half into other buffer
      int nx = it + 1;
      int nt2 = nx >> 5, ns = (nx >> 1) & 15, nk = nx & 1;
      const unsigned short* hstage = hbase + (size_t)nt2*4194304 + ns*16384 + (nk*4 + wid)*2048;
      unsigned short* lb = Bts + nk*8320 + wid*2080;
#pragma unroll
      for (int c = 0; c < 4; ++c)
        async_cp16(lb + c*512, hstage + c*512 + lane*8);
    }
    if (kk && it + 1 < 96) {              // prefetch mask for next (t,st)
      int gid = (it + 1) >> 1;
      int nt2 = gid >> 4, ns = gid & 15;
      nm = mb[(size_t)nt2*262144 + ns*1024 + ir0];
    }

    // table chunks for this 32-k slice (uniform-per-quad addresses -> L1 broadcast)
    const int koff = tt*16384 + st*64 + kk*32 + quad*8;
    const float* e1p = e1b + koff;
    const float* e2p = e2b + koff;
    float4 ea = *(const float4*)(e1p);
    float4 eb4 = *(const float4*)(e1p + 4);
    float4 ec = *(const float4*)(e2p);
    float4 ed = *(const float4*)(e2p + 4);
    float e1v[8] = {ea.x, ea.y, ea.z, ea.w, eb4.x, eb4.y, eb4.z, eb4.w};
    float e2v[8] = {ec.x, ec.y, ec.z, ec.w, ed.x, ed.y, ed.z, ed.w};

    const int kloc = kk*32 + quad*8;
    unsigned mq = (unsigned)(mw >> kloc);   // 8 mask bits in [7:0]
    union { bf16x8 v; unsigned u[4]; } ua;
    if (!anyPZ) {                          // hot path: unmasked p is exactly 0
#pragma unroll
      for (int p = 0; p < 4; ++p) {
        float pm0 = fmaxf(e1v[2*p]*E1v,   e2v[2*p]*E2v);
        float pm1 = fmaxf(e1v[2*p+1]*E1v, e2v[2*p+1]*E2v);
        unsigned m0 = (unsigned)(-(int)((mq >> (2*p))   & 1u));
        unsigned m1 = (unsigned)(-(int)((mq >> (2*p+1)) & 1u));
        float p0 = __uint_as_float(m0 & __float_as_uint(pm0));
        float p1 = __uint_as_float(m1 & __float_as_uint(pm1));
        ua.u[p] = pack_bf16x2(p0, p1);
      }
    } else {                               // rare: some row in wave is empty
#pragma unroll
      for (int p = 0; p < 4; ++p) {
        float pm0 = fmaxf(e1v[2*p]*E1v,   e2v[2*p]*E2v);
        float pm1 = fmaxf(e1v[2*p+1]*E1v, e2v[2*p+1]*E2v);
        float p0 = ((mq >> (2*p))   & 1u) ? pm0 : PZv;
        float p1 = ((mq >> (2*p+1)) & 1u) ? pm1 : PZv;
        ua.u[p] = pack_bf16x2(p0, p1);
      }
    }
    const unsigned short* bbase = Bts + kk*8320 + quad*2080;
#pragma unroll
    for (int cb = 0; cb < 16; ++cb) {
      bf16x8 bf = *(const bf16x8*)(bbase + (cb*16 + me)*8);
      acc[cb] = __builtin_amdgcn_mfma_f32_16x16x32_bf16(ua.v, bf, acc[cb], 0, 0, 0);
    }
  }

  // epilogue: plain stores (each (kl,b,row,f) written exactly once)
  {
    int io = i0w + quad*4;
#pragma unroll
    for (int cb = 0; cb < 16; ++cb) {
      int f = cb*16 + me;
      float* hp = H32 + (((size_t)b*1024 + io)*3 + kl)*256 + f;
#pragma unroll
      for (int r = 0; r < 4; ++r)
        hp[(size_t)r*768] = acc[cb][r];
    }
  }
}

// ---------------- fused layer attention + combine (R15) ----------------

__global__ __launch_bounds__(256) void k_scorecomb(
    const float* __restrict__ H32, const float* __restrict__ Ww,
    const float* __restrict__ bwv, const float* __restrict__ Wcv,
    float* __restrict__ out)
{
  __shared__ unsigned short Bs[8*7*64*8];   // 57344 B
  __shared__ float bwL[128], WcL[128];
  __shared__ float svL[192];
  const int tid = threadIdx.x, lane = tid & 63, wid = tid >> 6;
  const int me = lane & 15, quad = lane >> 4;
  for (int idx = tid; idx < 3584; idx += 256) {
    int kk = idx / 448, rem = idx % 448;
    int cb = rem >> 6, l = rem & 63;
    int n = cb*16 + (l & 15);
    int kbase = kk*32 + (l >> 4)*8;
    ushort4 lo, hi;
    if (n < 100) {
      const float* wp = Ww + (size_t)kbase*100 + n;
      lo.x = f2bf(wp[0]);   lo.y = f2bf(wp[100]); lo.z = f2bf(wp[200]); lo.w = f2bf(wp[300]);
      hi.x = f2bf(wp[400]); hi.y = f2bf(wp[500]); hi.z = f2bf(wp[600]); hi.w = f2bf(wp[700]);
    } else {
      lo.x=lo.y=lo.z=lo.w=0; hi.x=hi.y=hi.z=hi.w=0;
    }
    ushort4* dst = (ushort4*)(Bs + (size_t)idx*8);
    dst[0] = lo; dst[1] = hi;
  }
  if (tid < 128) {
    bwL[tid] = (tid < 100) ? bwv[tid] : 0.0f;
    WcL[tid] = (tid < 100) ? Wcv[tid] : 0.0f;
  }
  __syncthreads();

  const int base = blockIdx.x*192;           // first H32 row of this block
  // ---- phase 1: score (3 row-tiles per wave) ----
#pragma unroll
  for (int j = 0; j < 3; ++j) {
    const int tile = wid + 4*j;              // 0..11
    const int row0 = base + tile*16;
    const float* Arow = H32 + (size_t)(row0 + me)*256;
    f32x4 acc[7] = {};
#pragma unroll
    for (int kk = 0; kk < 8; ++kk) {
      const float* ap = Arow + kk*32 + quad*8;
      float4 a0 = *(const float4*)(ap);
      float4 a1 = *(const float4*)(ap + 4);
      union { bf16x8 v; unsigned u[4]; } ua;
      ua.u[0] = pack_bf16x2(a0.x, a0.y);
      ua.u[1] = pack_bf16x2(a0.z, a0.w);
      ua.u[2] = pack_bf16x2(a1.x, a1.y);
      ua.u[3] = pack_bf16x2(a1.z, a1.w);
#pragma unroll
      for (int cb = 0; cb < 7; ++cb) {
        bf16x8 bf = *(const bf16x8*)(Bs + ((size_t)(kk*7 + cb)*64 + lane)*8);
        acc[cb] = __builtin_amdgcn_mfma_f32_16x16x32_bf16(ua.v, bf, acc[cb], 0, 0, 0);
      }
    }
#pragma unroll
    for (int r = 0; r < 4; ++r) {
      float contrib = 0.0f;
#pragma unroll
      for (int cb = 0; cb < 7; ++cb) {
        int col = cb*16 + me;
        contrib += tanh_fast(acc[cb][r] + bwL[col]) * WcL[col];
      }
      contrib += __shfl_xor(contrib, 1);
      contrib += __shfl_xor(contrib, 2);
      contrib += __shfl_xor(contrib, 4);
      contrib += __shfl_xor(contrib, 8);
      if (me == 0) svL[tile*16 + quad*4 + r] = contrib;
    }
  }
  __syncthreads();

  // ---- phase 2: combine (64 bn x 64 f-quads = 4096 items) ----
  const int bn0 = blockIdx.x*64;
#pragma unroll
  for (int it2 = 0; it2 < 16; ++it2) {
    int item = it2*256 + tid;
    int bnl = item >> 6, fq = item & 63;
    float s0 = svL[bnl*3], s1 = svL[bnl*3+1], s2 = svL[bnl*3+2];
    float mm = fmaxf(s0, fmaxf(s1, s2));
    float e0 = fexp2((s0-mm)*L2E), e1 = fexp2((s1-mm)*L2E), e2 = fexp2((s2-mm)*L2E);
    float inv = frcp(e0 + e1 + e2);
    const float* hrow = H32 + (size_t)(base + bnl*3)*256 + fq*4;
    f32x4 h0 = *(const f32x4*)(hrow);
    f32x4 h1 = *(const f32x4*)(hrow + 256);
    f32x4 h2 = *(const f32x4*)(hrow + 512);
    f32x4 r = (e0*h0 + e1*h1 + e2*h2)*inv;
    *((f32x4*)out + (size_t)(bn0 + bnl)*64 + fq) = r;
  }
}

// ---------------- launcher ----------------

extern "C" void kernel_launch(void* const* d_in, const int* in_sizes, int n_in,
                              void* d_out, int out_size, void* d_ws, size_t ws_size,
                              hipStream_t stream) {
  const float* adj = (const float*)d_in[0];
  const float* X   = (const float*)d_in[1];
  const float* W   = (const float*)d_in[2];
  const float* a1  = (const float*)d_in[3];
  const float* a2  = (const float*)d_in[4];
  const float* Ww  = (const float*)d_in[5];
  const float* bw  = (const float*)d_in[6];
  const float* Wc  = (const float*)d_in[7];
  float* out = (float*)d_out;
  char* ws = (char*)d_ws;

  unsigned short* Xs  = (unsigned short*)(ws + 0);
  unsigned short* Wb  = (unsigned short*)(ws + 16777216);
  float* H32          = (float*)(ws + 0);                // reuses Xs/Wb region
  unsigned short* hsw = (unsigned short*)(ws + 50331648);
  u64* mbA            = (u64*)(ws + 125829120);
  float* rowE1        = (float*)(ws + 125829120);        // mbA lvl0, dead after boolmm-1
  float* rowE2        = (float*)(ws + 126418944);
  float* rowPZ        = (float*)(ws + 127008768);
  u64* mbT            = (u64*)(ws + 138412032);
  float* fbuf         = (float*)(ws + 157286400);
  float* etab1        = (float*)(ws + 158466048);
  float* etab2        = (float*)(ws + 159055872);

  k_prep<<<6016, 256, 0, stream>>>(adj, X, W, a1, a2, mbA, mbT, Xs, Wb);
  k_boolmm<<<3072, 256, 0, stream>>>(mbA, mbA, mbA + 786432, mbT, 3);
  // adj^3 = adj * adj^2 (A = sparse level0) instead of adj^2 * adj
  k_boolmm<<<3072, 256, 0, stream>>>(mbA, mbA + 786432, (u64*)nullptr, mbT, 6);
  k_gemm_h<<<2432, 256, 0, stream>>>(Xs, Wb, hsw, fbuf, etab1, etab2);
  k_rowstats<<<36864, 256, 0, stream>>>(mbT, fbuf, rowE1, rowE2, rowPZ);
  k_attgemm<<<768, 256, 0, stream>>>(hsw, etab1, etab2, rowE1, rowE2, rowPZ, mbT, H32);
  k_scorecomb<<<256, 256, 0, stream>>>(H32, Ww, bw, Wc, out);
}

// Round 9
// 676.254 us; speedup vs baseline: 1.5525x; 1.5525x over previous
//
#include <hip/hip_runtime.h>

// MOGCN on MI355X. Pipeline:
//  k_prep     : merged prep (R13): bitpack v2 / xconv v2 / build_wb / wb a-dots
//  k_boolmm   : boolean power masks; run2 computes adj^3 = adj * adj^2 (sparse A)
//  k_gemm_h   : X@W bf16 MFMA -> h + f1L/f2L + etab (R12 dbuf stage-ahead)
//  k_rowstats : log2-domain softmax stats -> per-row E1, E2, PZ
//  k_attgemm  : R9 version verbatim - FINAL at ~130us. Record: R7 (conflict-free
//               32x32), R9 (-5pp VALU), R10 (3-ring counted vmcnt), R11 (halved
//               LDS reads), R14 (2x occupancy, confirmed 51%), R16 (kl=0 sparse
//               gather: serial 900cy chain -> 507us, conflicts 2/3 as predicted
//               but pure latency death) ALL null-or-negative. Frozen.
//  k_scorecomb: R17: R15 fusion, split 256->512 blocks (96 rows/block, 6 tiles,
//               2 blocks/CU = 8 waves/CU) for latency hiding in the H32-load +
//               MFMA phase. LDS 58KB x 2 = 117KB/CU ok.
//
// Workspace map (bytes), total 159,842,304 (~152.4 MiB):
//  [0)            Xs bf16 16,777,216 | Wb bf16 @16,777,216 (2,490,368)  -- dead after k_gemm_h
//  [0)            H32 fp32 50,331,648 (reuses region above; fully written by k_attgemm)
//  [50,331,648)   hsw bf16 75,497,472   [9][16][128][256][8]
//  [125,829,120)  mbA u64 12,582,912; lvl0 dead after boolmm-1 -> rowE1/rowE2/rowPZ
//  [138,412,032)  mbT u64 18,874,368    [9][16][16w][1024i]
//  [157,286,400)  fbuf fp32 1,179,648   [2][9][16384]  (values pre-scaled by log2e)
//  [158,466,048)  etab1 589,824 | [159,055,872) etab2 589,824

typedef unsigned long long u64;
typedef __attribute__((ext_vector_type(4))) float f32x4;
typedef __attribute__((ext_vector_type(8))) short bf16x8;

#define NEGF (-9.0e15f)
#define L2E 1.44269504f

__device__ __forceinline__ float fexp2(float x){
#if __has_builtin(__builtin_amdgcn_exp2f)
  return __builtin_amdgcn_exp2f(x);
#else
  return exp2f(x);
#endif
}
__device__ __forceinline__ float flog2(float x){
#if __has_builtin(__builtin_amdgcn_logf)
  return __builtin_amdgcn_logf(x);
#else
  return log2f(x);
#endif
}
__device__ __forceinline__ float frcp(float x){
#if __has_builtin(__builtin_amdgcn_rcpf)
  return __builtin_amdgcn_rcpf(x);
#else
  return 1.0f/x;
#endif
}
__device__ __forceinline__ unsigned short f2bf(float x){   // RNE
  union { float f; unsigned u; } a; a.f = x;
  unsigned r = a.u + 0x7FFFu + ((a.u >> 16) & 1u);
  return (unsigned short)(r >> 16);
}
__device__ __forceinline__ float bf2f(unsigned short h){
  union { unsigned u; float f; } a; a.u = ((unsigned)h) << 16; return a.f;
}
__device__ __forceinline__ unsigned pack_bf16x2(float lo, float hi){ // fast round
  union { float f; unsigned u; } a, b; a.f = lo; b.f = hi;
  unsigned ul = a.u + 0x8000u, uh = b.u + 0x8000u;
#if __has_builtin(__builtin_amdgcn_perm)
  return __builtin_amdgcn_perm(uh, ul, 0x07060302u);
#else
  return (ul >> 16) | (uh & 0xFFFF0000u);
#endif
}
__device__ __forceinline__ float tanh_fast(float x){
  float e = fexp2(x * 2.885390082f);  // exp(2x)
  return 1.0f - 2.0f*frcp(e + 1.0f);
}
__device__ __forceinline__ void async_cp16(void* lds, const void* g){
  __builtin_amdgcn_global_load_lds(
      (const __attribute__((address_space(1))) unsigned int*)g,
      (__attribute__((address_space(3))) unsigned int*)lds, 16, 0, 0);
}

// ---------------- merged prep kernel (R13) ----------------

__global__ void k_prep(const float* __restrict__ adj, const float* __restrict__ X,
                       const float* __restrict__ W, const float* __restrict__ a1,
                       const float* __restrict__ a2,
                       u64* __restrict__ mbA0, u64* __restrict__ mbT,
                       unsigned short* __restrict__ Xs, unsigned short* __restrict__ Wb)
{
  int blk = blockIdx.x;
  const int lane = threadIdx.x & 63;
  if (blk < 3072) {
    // ---- bitpack v2: wave <-> contiguous 4KB chunk (64 words) ----
    int wg = blk*4 + (threadIdx.x >> 6);        // chunk id 0..12287
    const float* ap = adj + (size_t)wg*4096;
    u64 mine = 0;
#pragma unroll
    for (int j = 0; j < 64; ++j) {
      u64 m = __ballot(ap[j*64 + lane] > 0.0f);
      if (lane == j) mine = m;
    }
    int Wd = wg*64 + lane;                      // word = ((b*3+t)*1024 + i)*16 + w
    int w = Wd & 15, i = (Wd >> 4) & 1023, bt = Wd >> 14;
    int t = bt % 3, b = bt / 3;                 // bt uniform per wave (4KB < bt block)
    mbA0[((size_t)(t*16 + b)*1024 + i)*16 + w] = mine;   // coalesced 512B per wave
    mbT[((size_t)(t*16 + b)*16 + w)*1024 + i] = mine;    // 16 x 32B segments
  } else if (blk < 5120) {
    // ---- xconv v2: lane reads one full 64B line (16 floats = 2 g-groups) ----
    int wg = (blk - 3072)*4 + (threadIdx.x >> 6);   // 0..8191
    int g2 = wg & 31;
    int bn = (wg >> 5)*64 + lane;
    const float* xp = X + (size_t)bn*512 + g2*16;
    float4 A = *(const float4*)(xp);
    float4 B = *(const float4*)(xp + 4);
    float4 C = *(const float4*)(xp + 8);
    float4 D = *(const float4*)(xp + 12);
    ushort4 lo, hi;
    lo.x=f2bf(A.x); lo.y=f2bf(A.y); lo.z=f2bf(A.z); lo.w=f2bf(A.w);
    hi.x=f2bf(B.x); hi.y=f2bf(B.y); hi.z=f2bf(B.z); hi.w=f2bf(B.w);
    ushort4* d0 = (ushort4*)(Xs + ((size_t)(2*g2)*16384 + bn)*8);
    d0[0] = lo; d0[1] = hi;
    lo.x=f2bf(C.x); lo.y=f2bf(C.y); lo.z=f2bf(C.z); lo.w=f2bf(C.w);
    hi.x=f2bf(D.x); hi.y=f2bf(D.y); hi.z=f2bf(D.z); hi.w=f2bf(D.w);
    ushort4* d1 = (ushort4*)(Xs + ((size_t)(2*g2 + 1)*16384 + bn)*8);
    d1[0] = lo; d1[1] = hi;
  } else if (blk < 5728) {
    // ---- build_wb main (transpose copy + zero fill; a-dots done by blk>=5728) ----
    int idx = (blk - 5120)*256 + threadIdx.x;       // g*2432 + c
    if (idx >= 64*2432) return;
    int c = idx % 2432, g = idx / 2432;
    unsigned short o[8];
    if (c < 2304) {
      int s = c >> 8, f = c & 255, t = s % 3, klq = s / 3;   // s = kl*3 + t
      const float* wp = W + ((size_t)(t*3 + klq)*512)*256 + f;
#pragma unroll
      for (int e = 0; e < 8; ++e) o[e] = f2bf(wp[(size_t)(g*8 + e)*256]);
    } else if (c >= 2322) {
#pragma unroll
      for (int e = 0; e < 8; ++e) o[e] = 0;
    } else {
      return;                                      // a-dot columns: dedicated waves
    }
    ushort4 lo, hi;
    lo.x=o[0]; lo.y=o[1]; lo.z=o[2]; lo.w=o[3];
    hi.x=o[4]; hi.y=o[5]; hi.z=o[6]; hi.w=o[7];
    ushort4* dst = (ushort4*)(Wb + (size_t)idx*8);
    dst[0] = lo; dst[1] = hi;
  } else {
    // ---- wb a-dots: one wave per (g, c2), lane-parallel over f ----
    int dw = (blk - 5728)*4 + (threadIdx.x >> 6);   // 0..1151
    if (dw >= 1152) return;
    int c2 = dw % 18, g = dw / 18;
    int s = c2 >> 1, t = s % 3, klq = s / 3;
    const float* av = ((c2 & 1) ? a2 : a1) + (t*3 + klq)*256;
    const float* wp = W + (size_t)(t*3 + klq)*512*256;
    float4 a4 = *(const float4*)(av + lane*4);
    unsigned short o[8];
#pragma unroll
    for (int e = 0; e < 8; ++e) {
      const float* wr = wp + (size_t)(g*8 + e)*256 + lane*4;
      float4 w4 = *(const float4*)(wr);
      float acc = w4.x*a4.x + w4.y*a4.y + w4.z*a4.z + w4.w*a4.w;
#pragma unroll
      for (int off = 32; off; off >>= 1) acc += __shfl_xor(acc, off);
      o[e] = f2bf(acc);
    }
    if (lane == 0) {
      int c = 2304 + c2;
      ushort4 lo, hi;
      lo.x=o[0]; lo.y=o[1]; lo.z=o[2]; lo.w=o[3];
      hi.x=o[4]; hi.y=o[5]; hi.z=o[6]; hi.w=o[7];
      ushort4* dst = (ushort4*)(Wb + ((size_t)g*2432 + c)*8);
      dst[0] = lo; dst[1] = hi;
    }
  }
}

__global__ void k_boolmm(const u64* __restrict__ A, const u64* __restrict__ Bm,
                         u64* __restrict__ outA, u64* __restrict__ outT, int sbase)
{
  int tid = blockIdx.x*256 + threadIdx.x;   // 48*1024*16
  int w = tid & 15, i = (tid >> 4) & 1023, tb = tid >> 14;
  const u64* Ar = A + ((size_t)tb*1024 + i)*16;
  const u64* Bb = Bm + (size_t)tb*16384;
  u64 acc = 0;
  for (int ww = 0; ww < 16; ++ww) {
    u64 aw = Ar[ww];
    while (aw) {
      int kk = __builtin_ctzll(aw);
      aw &= aw - 1;
      acc |= Bb[((size_t)(ww*64 + kk))*16 + w];
    }
  }
  if (outA) outA[((size_t)tb*1024 + i)*16 + w] = acc;
  int t = tb >> 4, bq = tb & 15;
  outT[(((size_t)(sbase + t)*16 + bq)*16 + w)*1024 + i] = acc;
}

// ---------------- h = X@W GEMM (bf16 MFMA), fused f1L/f2L + etab ----------------
// R12: 16 half-steps of 32 k; half-tiles double-buffered; stage-ahead skeleton.

__global__ __launch_bounds__(256) void k_gemm_h(
    const unsigned short* __restrict__ Xs, const unsigned short* __restrict__ Wb,
    unsigned short* __restrict__ hsw, float* __restrict__ fbuf,
    float* __restrict__ et1, float* __restrict__ et2)
{
  __shared__ unsigned short Asl[2*4*132*8 + 8];   // 2 half-buffers x [4 kg][132][8]
  __shared__ unsigned short Bsl[2*4*132*8 + 8];
  const int tid = threadIdx.x, lane = tid & 63, wid = tid >> 6;
  int vb = blockIdx.x;                       // XCD swizzle: same mt -> same XCD
  int xc = vb & 7, mrest = vb >> 3;
  int mt = xc + 8*(mrest/19), nt = mrest % 19;
  const int M0 = mt << 7, N0 = nt << 7;
  const int wr = (wid >> 1) << 6, wc = (wid & 1) << 6;
  const int me = lane & 15;
  const int kgl = lane >> 4;                 // k-group within half (0..3)
  f32x4 acc[4][4] = {};

  // stage half 0: wave wid stages k-group wid (A rows 0..127, B cols 0..127)
  {
    const unsigned short* gA = Xs + ((size_t)wid*16384 + (M0 + lane))*8;
    const unsigned short* gB = Wb + ((size_t)wid*2432  + (N0 + lane))*8;
    unsigned short* la = Asl + (wid*132)*8;
    unsigned short* lb = Bsl + (wid*132)*8;
    async_cp16(la,        gA);
    async_cp16(la + 64*8, gA + (size_t)64*8);
    async_cp16(lb,        gB);
    async_cp16(lb + 64*8, gB + (size_t)64*8);
  }

  for (int h = 0; h < 16; ++h) {
    __syncthreads();                         // drains vmcnt: half-h loads landed
    if (h + 1 < 16) {                        // stage half h+1 into other buffer
      int kg = (h + 1)*4 + wid;
      const unsigned short* gA = Xs + ((size_t)kg*16384 + (M0 + lane))*8;
      const unsigned short* gB = Wb + ((size_t)kg*2432  + (N0 + lane))*8;
      unsigned short* la = Asl + (((h + 1 & 1)*4 + wid)*132)*8;
      unsigned short* lb = Bsl + (((h + 1 & 1)*4 + wid)*132)*8;
      async_cp16(la,        gA);
      async_cp16(la + 64*8, gA + (size_t)64*8);
      async_cp16(lb,        gB);
      async_cp16(lb + 64*8, gB + (size_t)64*8);
    }
    const unsigned short* Ah = Asl + ((h & 1)*4*132)*8;
    const unsigned short* Bh = Bsl + ((h & 1)*4*132)*8;
    bf16x8 afr[4], bfr[4];
#pragma unroll
    for (int rb = 0; rb < 4; ++rb)
      afr[rb] = *(const bf16x8*)(Ah + (kgl*132 + wr + rb*16 + me)*8);
#pragma unroll
    for (int cb = 0; cb < 4; ++cb)
      bfr[cb] = *(const bf16x8*)(Bh + (kgl*132 + wc + cb*16 + me)*8);
#pragma unroll
    for (int rb = 0; rb < 4; ++rb)
#pragma unroll
      for (int cb = 0; cb < 4; ++cb)
        acc[rb][cb] = __builtin_amdgcn_mfma_f32_16x16x32_bf16(afr[rb], bfr[cb], acc[rb][cb], 0, 0, 0);
  }

  const int quad = lane >> 4;
#pragma unroll
  for (int rb = 0; rb < 4; ++rb) {
    int jbase = M0 + wr + rb*16 + quad*4;
    int bidx = jbase >> 10, jn = jbase & 1023;
#pragma unroll
    for (int cb = 0; cb < 4; ++cb) {
      int c = N0 + wc + cb*16 + me;
      f32x4 v = acc[rb][cb];
      if (c < 2304) {
        int s = c >> 8, f = c & 255;
        ushort4 pk;
        pk.x = f2bf(v[0]); pk.y = f2bf(v[1]); pk.z = f2bf(v[2]); pk.w = f2bf(v[3]);
        *(ushort4*)(hsw + (size_t)s*4194304 + (size_t)bidx*262144 + ((jn>>3)*256 + f)*8 + (jn&7)) = pk;
      } else if (c < 2322) {
        int c2 = c - 2304, s = c2 >> 1, wh = c2 & 1;
        f32x4 vl = v * L2E;                   // log2 domain
        *(f32x4*)(fbuf + (size_t)wh*147456 + s*16384 + jbase) = vl;
        if (wh) {                             // etab fold: e1k=2^f2L, e2k=2^(.2 f2L)
#pragma unroll
          for (int r = 0; r < 4; ++r) {
            et1[s*16384 + jbase + r] = fexp2(vl[r]);
            et2[s*16384 + jbase + r] = fexp2(0.2f*vl[r]);
          }
        }
      }
    }
  }
}

// ---------------- per-row softmax stats (log2 domain internally) ----------------

__global__ __launch_bounds__(256) void k_rowstats(
    const u64* __restrict__ mbT, const float* __restrict__ fbuf,
    float* __restrict__ rowE1, float* __restrict__ rowE2, float* __restrict__ rowPZ)
{
  int gw = blockIdx.x*4 + (threadIdx.x >> 6);   // row id: (s*16+b)*1024 + i
  int lane = threadIdx.x & 63;
  int i = gw & 1023, sb = gw >> 10;
  int b = sb & 15, s = sb >> 4;
  const u64* mrow = mbT + (size_t)sb*16384 + i;
  const float* f1g = fbuf + s*16384 + b*1024;
  const float* f2g = fbuf + 147456 + s*16384 + b*1024;
  float f1i = f1g[i];
  float vals[16];
  float mmax = NEGF;
#pragma unroll
  for (int w = 0; w < 16; ++w) {
    u64 word = mrow[(size_t)w*1024];
    float u0 = f1i + f2g[w*64 + lane];          // (f1+f2)*log2e
    float lk = fmaxf(u0, 0.2f*u0);              // leaky in log2 domain
    float val = ((word >> lane) & 1ull) ? lk : NEGF;
    vals[w] = val;
    mmax = fmaxf(mmax, val);
  }
#pragma unroll
  for (int off = 32; off; off >>= 1) mmax = fmaxf(mmax, __shfl_xor(mmax, off));
  float l = 0.0f;
#pragma unroll
  for (int w = 0; w < 16; ++w) l += fexp2(vals[w] - mmax);
#pragma unroll
  for (int off = 32; off; off >>= 1) l += __shfl_xor(l, off);
  if (lane == 0) {
    bool empty = (mmax < -8.0e15f);
    float C = (empty ? 0.0f : -mmax) - flog2(l);
    rowE1[gw] = fexp2(f1i + C);
    rowE2[gw] = fexp2(0.2f*f1i + C);
    rowPZ[gw] = empty ? fexp2(C) : 0.0f;        // exact 0 for non-empty rows
  }
}

// ---------------- fused attention GEMM: H = sum_t softmax(mask_t(e_t)) @ h_t --------
// R9 version verbatim (measured ~130us) - FINAL, see header note.

__global__ __launch_bounds__(256, 3) void k_attgemm(
    const unsigned short* __restrict__ hsw,
    const float* __restrict__ et1g, const float* __restrict__ et2g,
    const float* __restrict__ rowE1, const float* __restrict__ rowE2,
    const float* __restrict__ rowPZ,
    const u64* __restrict__ mbT, float* __restrict__ H32)
{
  __shared__ unsigned short Bts[2*4*260*8];   // 2 half-buffers, 16640B each
  const int tid = threadIdx.x, lane = tid & 63, wid = tid >> 6;
  const int me = lane & 15, quad = lane >> 4;
  int vb = blockIdx.x;
  int mt = vb / 48, g = vb % 48;              // g%8 constant across a group's 16 blocks
  int kl = g >> 4, b = g & 15;
  const int i0w = mt*64 + wid*16;
  const int ir0 = i0w + me;
  const unsigned short* hbase = hsw + (size_t)(kl*3)*4194304 + (size_t)b*262144;
  const float* e1b = et1g + (kl*3)*16384 + b*1024;   // e1k table
  const float* e2b = et2g + (kl*3)*16384 + b*1024;   // e2k table
  const float* E1b = rowE1 + ((kl*3)*16 + b)*1024;
  const float* E2b = rowE2 + ((kl*3)*16 + b)*1024;
  const float* PZb = rowPZ + ((kl*3)*16 + b)*1024;
  const u64* mb = mbT + (size_t)((kl*3)*16 + b)*16384;   // t-stride 262144 u64

  float E1v, E2v, PZv;
  int anyPZ = 0;
  f32x4 acc[16] = {};

  // seed: stage iter 0 (t=0, st=0, ks=0) into buffer 0
  {
    const unsigned short* hstage = hbase + wid*2048;
    unsigned short* lb = Bts + wid*2080;
#pragma unroll
    for (int c = 0; c < 4; ++c)
      async_cp16(lb + c*512, hstage + c*512 + lane*8);
  }
  u64 mw = mb[ir0];
  u64 nm = 0;

  for (int it = 0; it < 96; ++it) {
    const int tt = it >> 5, kk = it & 1;
    const int st = (it >> 1) & 15;
    if ((it & 31) == 0) {                 // t boundary: per-row constants for this t
      E1v = E1b[tt*16384 + ir0];
      E2v = E2b[tt*16384 + ir0];
      PZv = PZb[tt*16384 + ir0];
      anyPZ = __any(PZv != 0.0f);
    }
    if (!kk && it) mw = nm;               // adopt prefetched mask

    __syncthreads();   // drains vmcnt: current half's loads issued one compute ago

    if (it + 1 < 96) {                    // stage next half into other buffer
      int nx = it + 1;
      int nt2 = nx >> 5, ns = (nx >> 1) & 15, nk = nx & 1;
      const unsigned short* hstage = hbase + (size_t)nt2*4194304 + ns*16384 + (nk*4 + wid)*2048;
      unsigned short* lb = Bts + nk*8320 + wid*2080;
#pragma unroll
      for (int c = 0; c < 4; ++c)
        async_cp16(lb + c*512, hstage + c*512 + lane*8);
    }
    if (kk && it + 1 < 96) {              // prefetch mask for next (t,st)
      int gid = (it + 1) >> 1;
      int nt2 = gid >> 4, ns = gid & 15;
      nm = mb[(size_t)nt2*262144 + ns*1024 + ir0];
    }

    // table chunks for this 32-k slice (uniform-per-quad addresses -> L1 broadcast)
    const int koff = tt*16384 + st*64 + kk*32 + quad*8;
    const float* e1p = e1b + koff;
    const float* e2p = e2b + koff;
    float4 ea = *(const float4*)(e1p);
    float4 eb4 = *(const float4*)(e1p + 4);
    float4 ec = *(const float4*)(e2p);
    float4 ed = *(const float4*)(e2p + 4);
    float e1v[8] = {ea.x, ea.y, ea.z, ea.w, eb4.x, eb4.y, eb4.z, eb4.w};
    float e2v[8] = {ec.x, ec.y, ec.z, ec.w, ed.x, ed.y, ed.z, ed.w};

    const int kloc = kk*32 + quad*8;
    unsigned mq = (unsigned)(mw >> kloc);   // 8 mask bits in [7:0]
    union { bf16x8 v; unsigned u[4]; } ua;
    if (!anyPZ) {                          // hot path: unmasked p is exactly 0
#pragma unroll
      for (int p = 0; p < 4; ++p) {
        float pm0 = fmaxf(e1v[2*p]*E1v,   e2v[2*p]*E2v);
        float pm1 = fmaxf(e1v[2*p+1]*E1v, e2v[2*p+1]*E2v);
        unsigned m0 = (unsigned)(-(int)((mq >> (2*p))   & 1u));
        unsigned m1 = (unsigned)(-(int)((mq >> (2*p+1)) & 1u));
        float p0 = __uint_as_float(m0 & __float_as_uint(pm0));
        float p1 = __uint_as_float(m1 & __float_as_uint(pm1));
        ua.u[p] = pack_bf16x2(p0, p1);
      }
    } else {                               // rare: some row in wave is empty
#pragma unroll
      for (int p = 0; p < 4; ++p) {
        float pm0 = fmaxf(e1v[2*p]*E1v,   e2v[2*p]*E2v);
        float pm1 = fmaxf(e1v[2*p+1]*E1v, e2v[2*p+1]*E2v);
        float p0 = ((mq >> (2*p))   & 1u) ? pm0 : PZv;
        float p1 = ((mq >> (2*p+1)) & 1u) ? pm1 : PZv;
        ua.u[p] = pack_bf16x2(p0, p1);
      }
    }
    const unsigned short* bbase = Bts + kk*8320 + quad*2080;
#pragma unroll
    for (int cb = 0; cb < 16; ++cb) {
      bf16x8 bf = *(const bf16x8*)(bbase + (cb*16 + me)*8);
      acc[cb] = __builtin_amdgcn_mfma_f32_16x16x32_bf16(ua.v, bf, acc[cb], 0, 0, 0);
    }
  }

  // epilogue: plain stores (each (kl,b,row,f) written exactly once)
  {
    int io = i0w + quad*4;
#pragma unroll
    for (int cb = 0; cb < 16; ++cb) {
      int f = cb*16 + me;
      float* hp = H32 + (((size_t)b*1024 + io)*3 + kl)*256 + f;
#pragma unroll
      for (int r = 0; r < 4; ++r)
        hp[(size_t)r*768] = acc[cb][r];
    }
  }
}

// ---------------- fused layer attention + combine ----------------
// R17: block = 96 H32 rows (32 bn), grid 512 -> 2 blocks/CU, 8 waves/CU for
// latency hiding. Phase 1 (score): 6 row-tiles -> svL. Phase 2 (combine):
// softmax over kl + weighted sum; H32 rows L2-hot from phase 1.

__global__ __launch_bounds__(256) void k_scorecomb(
    const float* __restrict__ H32, const float* __restrict__ Ww,
    const float* __restrict__ bwv, const float* __restrict__ Wcv,
    float* __restrict__ out)
{
  __shared__ unsigned short Bs[8*7*64*8];   // 57344 B
  __shared__ float bwL[128], WcL[128];
  __shared__ float svL[96];
  const int tid = threadIdx.x, lane = tid & 63, wid = tid >> 6;
  const int me = lane & 15, quad = lane >> 4;
  for (int idx = tid; idx < 3584; idx += 256) {
    int kk = idx / 448, rem = idx % 448;
    int cb = rem >> 6, l = rem & 63;
    int n = cb*16 + (l & 15);
    int kbase = kk*32 + (l >> 4)*8;
    ushort4 lo, hi;
    if (n < 100) {
      const float* wp = Ww + (size_t)kbase*100 + n;
      lo.x = f2bf(wp[0]);   lo.y = f2bf(wp[100]); lo.z = f2bf(wp[200]); lo.w = f2bf(wp[300]);
      hi.x = f2bf(wp[400]); hi.y = f2bf(wp[500]); hi.z = f2bf(wp[600]); hi.w = f2bf(wp[700]);
    } else {
      lo.x=lo.y=lo.z=lo.w=0; hi.x=hi.y=hi.z=hi.w=0;
    }
    ushort4* dst = (ushort4*)(Bs + (size_t)idx*8);
    dst[0] = lo; dst[1] = hi;
  }
  if (tid < 128) {
    bwL[tid] = (tid < 100) ? bwv[tid] : 0.0f;
    WcL[tid] = (tid < 100) ? Wcv[tid] : 0.0f;
  }
  __syncthreads();

  const int base = blockIdx.x*96;            // first H32 row of this block
  // ---- phase 1: score (6 row-tiles; waves 0-3 at j=0, waves 0-1 at j=1) ----
#pragma unroll
  for (int j = 0; j < 2; ++j) {
    const int tile = wid + 4*j;              // 0..7, guard to 6
    if (tile < 6) {
      const int row0 = base + tile*16;
      const float* Arow = H32 + (size_t)(row0 + me)*256;
      f32x4 acc[7] = {};
#pragma unroll
      for (int kk = 0; kk < 8; ++kk) {
        const float* ap = Arow + kk*32 + quad*8;
        float4 a0 = *(const float4*)(ap);
        float4 a1 = *(const float4*)(ap + 4);
        union { bf16x8 v; unsigned u[4]; } ua;
        ua.u[0] = pack_bf16x2(a0.x, a0.y);
        ua.u[1] = pack_bf16x2(a0.z, a0.w);
        ua.u[2] = pack_bf16x2(a1.x, a1.y);
        ua.u[3] = pack_bf16x2(a1.z, a1.w);
#pragma unroll
        for (int cb = 0; cb < 7; ++cb) {
          bf16x8 bf = *(const bf16x8*)(Bs + ((size_t)(kk*7 + cb)*64 + lane)*8);
          acc[cb] = __builtin_amdgcn_mfma_f32_16x16x32_bf16(ua.v, bf, acc[cb], 0, 0, 0);
        }
      }
#pragma unroll
      for (int r = 0; r < 4; ++r) {
        float contrib = 0.0f;
#pragma unroll
        for (int cb = 0; cb < 7; ++cb) {
          int col = cb*16 + me;
          contrib += tanh_fast(acc[cb][r] + bwL[col]) * WcL[col];
        }
        contrib += __shfl_xor(contrib, 1);
        contrib += __shfl_xor(contrib, 2);
        contrib += __shfl_xor(contrib, 4);
        contrib += __shfl_xor(contrib, 8);
        if (me == 0) svL[tile*16 + quad*4 + r] = contrib;
      }
    }
  }
  __syncthreads();

  // ---- phase 2: combine (32 bn x 64 f-quads = 2048 items) ----
  const int bn0 = blockIdx.x*32;
#pragma unroll
  for (int it2 = 0; it2 < 8; ++it2) {
    int item = it2*256 + tid;
    int bnl = item >> 6, fq = item & 63;
    float s0 = svL[bnl*3], s1 = svL[bnl*3+1], s2 = svL[bnl*3+2];
    float mm = fmaxf(s0, fmaxf(s1, s2));
    float e0 = fexp2((s0-mm)*L2E), e1 = fexp2((s1-mm)*L2E), e2 = fexp2((s2-mm)*L2E);
    float inv = frcp(e0 + e1 + e2);
    const float* hrow = H32 + (size_t)(base + bnl*3)*256 + fq*4;
    f32x4 h0 = *(const f32x4*)(hrow);
    f32x4 h1 = *(const f32x4*)(hrow + 256);
    f32x4 h2 = *(const f32x4*)(hrow + 512);
    f32x4 r = (e0*h0 + e1*h1 + e2*h2)*inv;
    *((f32x4*)out + (size_t)(bn0 + bnl)*64 + fq) = r;
  }
}

// ---------------- launcher ----------------

extern "C" void kernel_launch(void* const* d_in, const int* in_sizes, int n_in,
                              void* d_out, int out_size, void* d_ws, size_t ws_size,
                              hipStream_t stream) {
  const float* adj = (const float*)d_in[0];
  const float* X   = (const float*)d_in[1];
  const float* W   = (const float*)d_in[2];
  const float* a1  = (const float*)d_in[3];
  const float* a2  = (const float*)d_in[4];
  const float* Ww  = (const float*)d_in[5];
  const float* bw  = (const float*)d_in[6];
  const float* Wc  = (const float*)d_in[7];
  float* out = (float*)d_out;
  char* ws = (char*)d_ws;

  unsigned short* Xs  = (unsigned short*)(ws + 0);
  unsigned short* Wb  = (unsigned short*)(ws + 16777216);
  float* H32          = (float*)(ws + 0);                // reuses Xs/Wb region
  unsigned short* hsw = (unsigned short*)(ws + 50331648);
  u64* mbA            = (u64*)(ws + 125829120);
  float* rowE1        = (float*)(ws + 125829120);        // mbA lvl0, dead after boolmm-1
  float* rowE2        = (float*)(ws + 126418944);
  float* rowPZ        = (float*)(ws + 127008768);
  u64* mbT            = (u64*)(ws + 138412032);
  float* fbuf         = (float*)(ws + 157286400);
  float* etab1        = (float*)(ws + 158466048);
  float* etab2        = (float*)(ws + 159055872);

  k_prep<<<6016, 256, 0, stream>>>(adj, X, W, a1, a2, mbA, mbT, Xs, Wb);
  k_boolmm<<<3072, 256, 0, stream>>>(mbA, mbA, mbA + 786432, mbT, 3);
  // adj^3 = adj * adj^2 (A = sparse level0) instead of adj^2 * adj
  k_boolmm<<<3072, 256, 0, stream>>>(mbA, mbA + 786432, (u64*)nullptr, mbT, 6);
  k_gemm_h<<<2432, 256, 0, stream>>>(Xs, Wb, hsw, fbuf, etab1, etab2);
  k_rowstats<<<36864, 256, 0, stream>>>(mbT, fbuf, rowE1, rowE2, rowPZ);
  k_attgemm<<<768, 256, 0, stream>>>(hsw, etab1, etab2, rowE1, rowE2, rowPZ, mbT, H32);
  k_scorecomb<<<512, 256, 0, stream>>>(H32, Ww, bw, Wc, out);
}